// Round 6
// baseline (188.493 us; speedup 1.0000x reference)
//
#include <hip/hip_runtime.h>
#include <hip/hip_fp16.h>

typedef _Float16 f16;
typedef _Float16 f16x8 __attribute__((ext_vector_type(8)));
typedef float f32x4 __attribute__((ext_vector_type(4)));

__device__ __forceinline__ f16x8 relu8(f16x8 a) {
  f16x8 r;
#pragma unroll
  for (int i = 0; i < 8; i++) r[i] = a[i] > (f16)0 ? a[i] : (f16)0;
  return r;
}

__device__ __forceinline__ f16x8 bcast8(f16 s) {
  return (f16x8){s, s, s, s, s, s, s, s};
}

// ---------------------------------------------------------------------------
// prep: Wtp[frag=cg*32+kb2][lane*8+e] = f16(W2[kb2*32+q*8+e][cg*16+cL])
// (B-fragment order for mfma_f32_16x16x32_f16; 1 KB contiguous per fragment)
// ---------------------------------------------------------------------------
__global__ __launch_bounds__(256) void k_prep(const float* __restrict__ W2,
                                              f16* __restrict__ Wtp) {
  const int t = blockIdx.x * 256 + threadIdx.x;
  const int frag = t >> 6, l = t & 63;
  const int cg = frag >> 5, kb2 = frag & 31;
  const int q = l >> 4, cL = l & 15;
  const int n = cg * 16 + cL, k0 = kb2 * 32 + q * 8;
  f16x8 o;
#pragma unroll
  for (int e = 0; e < 8; e++) o[e] = (f16)W2[(k0 + e) * 128 + n];
  *(f16x8*)(Wtp + frag * 512 + l * 8) = o;
}

// ---------------------------------------------------------------------------
// fused: block = (jt, strip, nh), 512 threads = 8 waves, 1 block/CU.
// Stage this nh's 64n x 1024k W2 fragments (128 KB) into LDS ONCE, then each
// wave processes 2 i-rows x 128 j x 64 n x 1024 k entirely from LDS/registers.
// Partial (over n-half) results go to Kp[nh]; atta sums the halves.
// ---------------------------------------------------------------------------
__global__ __launch_bounds__(512) void k_fused(
    const float* __restrict__ x, const float* __restrict__ W1,
    const float* __restrict__ b1, const float* __restrict__ b2,
    const float* __restrict__ W3, const float* __restrict__ b3,
    const f16* __restrict__ Wtp,
    float* __restrict__ Kp0, float* __restrict__ Kp1) {
  __shared__ f16 w2f[65536];                 // 128 KB: this nh's B-fragments
  __shared__ f16 w1a[1024], w1bt[1024], b1t[1024];

  const int tid = threadIdx.x;
  const int jt = blockIdx.x, s = blockIdx.y, nh = blockIdx.z;
  const int i0 = s * 16, j0 = jt * 128;
  if (i0 > j0 + 127) return;                 // strip entirely below diagonal
  float* __restrict__ Kp = nh ? Kp1 : Kp0;

  // --- stage W2 fragments: contiguous 128 KB slice of Wtp
  {
    const f16* src = Wtp + nh * 65536;
    #pragma unroll
    for (int p = 0; p < 16; p++) {
      const int off = p * 4096 + tid * 8;
      *(f16x8*)(&w2f[off]) = *(const f16x8*)(src + off);
    }
  }
  // --- stage W1 row tables (f16)
  if (tid < 128) {
    const int c8 = tid << 3;
    const float4 a0 = *(const float4*)(W1 + c8);
    const float4 a1 = *(const float4*)(W1 + c8 + 4);
    const float4 g0 = *(const float4*)(b1 + c8);
    const float4 g1 = *(const float4*)(b1 + c8 + 4);
    f16x8 oa, og;
    oa[0] = (f16)a0.x; oa[1] = (f16)a0.y; oa[2] = (f16)a0.z; oa[3] = (f16)a0.w;
    oa[4] = (f16)a1.x; oa[5] = (f16)a1.y; oa[6] = (f16)a1.z; oa[7] = (f16)a1.w;
    og[0] = (f16)g0.x; og[1] = (f16)g0.y; og[2] = (f16)g0.z; og[3] = (f16)g0.w;
    og[4] = (f16)g1.x; og[5] = (f16)g1.y; og[6] = (f16)g1.z; og[7] = (f16)g1.w;
    *(f16x8*)(&w1a[c8]) = oa;
    *(f16x8*)(&b1t[c8]) = og;
  } else if (tid < 256) {
    const int c8 = (tid - 128) << 3;
    const float4 a0 = *(const float4*)(W1 + 1024 + c8);
    const float4 a1 = *(const float4*)(W1 + 1024 + c8 + 4);
    f16x8 ob;
    ob[0] = (f16)a0.x; ob[1] = (f16)a0.y; ob[2] = (f16)a0.z; ob[3] = (f16)a0.w;
    ob[4] = (f16)a1.x; ob[5] = (f16)a1.y; ob[6] = (f16)a1.z; ob[7] = (f16)a1.w;
    *(f16x8*)(&w1bt[c8]) = ob;
  }
  __syncthreads();

  const int lane = tid & 63, wv = tid >> 6;  // 8 waves; wave owns 2 i-rows
  const int cL = lane & 15, q = lane >> 4;

  // per-lane x_j for the 8 j-groups (A-frag m-index = cL)
  f16 xjs[8];
  #pragma unroll
  for (int rg = 0; rg < 8; rg++) xjs[rg] = (f16)x[j0 + rg * 16 + cL];

  float b2v[4], w3v[4];
  #pragma unroll
  for (int cg = 0; cg < 4; cg++) {
    b2v[cg] = b2[nh * 64 + cg * 16 + cL];
    w3v[cg] = W3[nh * 64 + cg * 16 + cL];
  }
  const float badd = (nh == 0) ? b3[0] : 0.f;  // b3 added exactly once

  for (int ii = 0; ii < 2; ++ii) {
    const int i = i0 + wv * 2 + ii;
    const f16 xih = (f16)x[i];
    const f16x8 xiv = bcast8(xih);

    f32x4 acc[8][4];
    #pragma unroll
    for (int rg = 0; rg < 8; rg++)
      #pragma unroll
      for (int cg = 0; cg < 4; cg++) acc[rg][cg] = (f32x4){0.f, 0.f, 0.f, 0.f};

    #pragma unroll 8
    for (int kk = 0; kk < 32; ++kk) {
      const int o = kk * 32 + q * 8;
      const f16x8 w1av = *(const f16x8*)(&w1a[o]);
      const f16x8 b1v  = *(const f16x8*)(&b1t[o]);
      const f16x8 w1bv = *(const f16x8*)(&w1bt[o]);
      const f16x8 hav = xiv * w1av + b1v;          // 4x v_pk_fma_f16
      f16x8 bf[4];
      #pragma unroll
      for (int cg = 0; cg < 4; cg++)
        bf[cg] = *(const f16x8*)(&w2f[(cg * 32 + kk) * 512 + lane * 8]);
      #pragma unroll
      for (int rg = 0; rg < 8; rg++) {
        const f16x8 af = relu8(bcast8(xjs[rg]) * w1bv + hav);
        #pragma unroll
        for (int cg = 0; cg < 4; cg++)
          acc[rg][cg] = __builtin_amdgcn_mfma_f32_16x16x32_f16(af, bf[cg], acc[rg][cg], 0, 0, 0);
      }
    }

    // --- epilogue row i: partial dot over this nh's 64 n
    #pragma unroll
    for (int rg = 0; rg < 8; rg++) {
      #pragma unroll
      for (int r = 0; r < 4; r++) {
        float ssum = 0.f;
        #pragma unroll
        for (int cg = 0; cg < 4; cg++)
          ssum = fmaf(fmaxf(acc[rg][cg][r] + b2v[cg], 0.f), w3v[cg], ssum);
        ssum += __shfl_xor(ssum, 1, 64);
        ssum += __shfl_xor(ssum, 2, 64);
        ssum += __shfl_xor(ssum, 4, 64);
        ssum += __shfl_xor(ssum, 8, 64);
        if (cL == 0) {
          const int j = j0 + rg * 16 + q * 4 + r;  // C row = q*4 + reg
          if (j >= i) Kp[i * 512 + j] = ssum + badd;
        }
      }
    }
  }
}

// ---------------------------------------------------------------------------
// atta: C = K^T K, K = Kp0 + Kp1 (summed on load). Below-diagonal entries
// UNWRITTEN -> masked to 0. Symmetry (pb<=qb + mirror), i-loop stops at pb+32.
// ---------------------------------------------------------------------------
__global__ __launch_bounds__(256) void k_atta(const float* __restrict__ K0,
                                              const float* __restrict__ K1,
                                              float* __restrict__ C) {
  const int pb = blockIdx.x * 32, qb = blockIdx.y * 32;
  if (pb > qb) return;
  __shared__ float sp[32][33], sq[32][33];
  const int tid = threadIdx.x;
  const int tx = tid & 15, ty = tid >> 4;
  float c00 = 0.f, c01 = 0.f, c10 = 0.f, c11 = 0.f;
  for (int i0 = 0; i0 < pb + 32; i0 += 32) {
    #pragma unroll
    for (int r = 0; r < 4; r++) {
      const int e = tid + 256 * r, ii = e >> 5, pp = e & 31;
      const int irow = i0 + ii;
      const int ip = irow * 512 + pb + pp, iq = irow * 512 + qb + pp;
      sp[ii][pp] = (irow <= pb + pp) ? K0[ip] + K1[ip] : 0.f;
      sq[ii][pp] = (irow <= qb + pp) ? K0[iq] + K1[iq] : 0.f;
    }
    __syncthreads();
    #pragma unroll 8
    for (int ii = 0; ii < 32; ii++) {
      const float a0 = sp[ii][ty * 2], a1 = sp[ii][ty * 2 + 1];
      const float b0 = sq[ii][tx * 2], b1 = sq[ii][tx * 2 + 1];
      c00 = fmaf(a0, b0, c00); c01 = fmaf(a0, b1, c01);
      c10 = fmaf(a1, b0, c10); c11 = fmaf(a1, b1, c11);
    }
    __syncthreads();
  }
  const int p0 = pb + ty * 2, q0 = qb + tx * 2;
  C[p0 * 512 + q0] = c00;       C[p0 * 512 + q0 + 1] = c01;
  C[(p0 + 1) * 512 + q0] = c10; C[(p0 + 1) * 512 + q0 + 1] = c11;
  C[q0 * 512 + p0] = c00;       C[(q0 + 1) * 512 + p0] = c01;
  C[q0 * 512 + p0 + 1] = c10;   C[(q0 + 1) * 512 + p0 + 1] = c11;
}

extern "C" void kernel_launch(void* const* d_in, const int* in_sizes, int n_in,
                              void* d_out, int out_size, void* d_ws, size_t ws_size,
                              hipStream_t stream) {
  const float* x  = (const float*)d_in[0];
  const float* W1 = (const float*)d_in[1];
  const float* b1 = (const float*)d_in[2];
  const float* W2 = (const float*)d_in[3];
  const float* b2 = (const float*)d_in[4];
  const float* W3 = (const float*)d_in[5];
  const float* b3 = (const float*)d_in[6];
  float* out = (float*)d_out;
  char* ws = (char*)d_ws;

  f16* Wtp   = (f16*)ws;                           // 256 KB packed W2 B-fragments
  float* Kp0 = (float*)(ws + (256 << 10));         // 1 MB partial (n 0..63)
  float* Kp1 = (float*)(ws + (256 << 10) + (1 << 20));  // 1 MB partial (n 64..127)

  k_prep<<<64, 256, 0, stream>>>(W2, Wtp);
  k_fused<<<dim3(4, 32, 2), 512, 0, stream>>>(x, W1, b1, b2, W3, b3, Wtp, Kp0, Kp1);
  k_atta<<<dim3(16, 16), 256, 0, stream>>>(Kp0, Kp1, out);
}

// Round 7
// 160.579 us; speedup vs baseline: 1.1738x; 1.1738x over previous
//
#include <hip/hip_runtime.h>
#include <hip/hip_fp16.h>

typedef _Float16 f16;
typedef _Float16 f16x8 __attribute__((ext_vector_type(8)));
typedef float f32x4 __attribute__((ext_vector_type(4)));

__device__ __forceinline__ f16x8 relu8(f16x8 a) {
#if __has_builtin(__builtin_elementwise_max)
  return __builtin_elementwise_max(a, (f16x8)(f16)0);   // v_pk_max_f16 x4
#else
  f16x8 r;
#pragma unroll
  for (int i = 0; i < 8; i++) r[i] = a[i] > (f16)0 ? a[i] : (f16)0;
  return r;
#endif
}

__device__ __forceinline__ f16x8 bcast8(f16 s) {
  return (f16x8){s, s, s, s, s, s, s, s};
}

// ---------------------------------------------------------------------------
// prep: Wtp[frag=cg*32+kb2][lane*8+e] = f16(W2[kb2*32+q*8+e][cg*16+cL])
// (B-fragment order for mfma_f32_16x16x32_f16; 1 KB contiguous per fragment)
// ---------------------------------------------------------------------------
__global__ __launch_bounds__(256) void k_prep(const float* __restrict__ W2,
                                              f16* __restrict__ Wtp) {
  const int t = blockIdx.x * 256 + threadIdx.x;
  const int frag = t >> 6, l = t & 63;
  const int cg = frag >> 5, kb2 = frag & 31;
  const int q = l >> 4, cL = l & 15;
  const int n = cg * 16 + cL, k0 = kb2 * 32 + q * 8;
  f16x8 o;
#pragma unroll
  for (int e = 0; e < 8; e++) o[e] = (f16)W2[(k0 + e) * 128 + n];
  *(f16x8*)(Wtp + frag * 512 + l * 8) = o;
}

// ---------------------------------------------------------------------------
// fused: block = (jt, strip, nh), 512 threads = 8 waves, 1 block/CU.
// W2 fragments for this n-half staged to LDS ONCE (128 KB); K-loop touches
// only LDS + registers. A-fragments regenerated in registers:
// relu(xj*w1b + (xi*w1a + b1)) via v_pk_fma/v_pk_max.
// launch_bounds(512,2): cap 256 unified VGPR/wave -> NO SCRATCH SPILL
// (R6 lesson: unroll-8 spilled acc -> 22.9 MB scratch writes -> 88 us).
// ---------------------------------------------------------------------------
__global__ __launch_bounds__(512, 2) void k_fused(
    const float* __restrict__ x, const float* __restrict__ W1,
    const float* __restrict__ b1, const float* __restrict__ b2,
    const float* __restrict__ W3, const float* __restrict__ b3,
    const f16* __restrict__ Wtp,
    float* __restrict__ Kp0, float* __restrict__ Kp1) {
  __shared__ f16 w2f[65536];                 // 128 KB: this nh's B-fragments
  __shared__ f16 w1a[1024], w1bt[1024], b1t[1024];

  const int tid = threadIdx.x;
  const int jt = blockIdx.x, s = blockIdx.y, nh = blockIdx.z;
  const int i0 = s * 16, j0 = jt * 128;
  if (i0 > j0 + 127) return;                 // strip entirely below diagonal
  float* __restrict__ Kp = nh ? Kp1 : Kp0;

  // --- stage W2 fragments: contiguous 128 KB slice of Wtp
  {
    const f16* src = Wtp + nh * 65536;
    #pragma unroll
    for (int p = 0; p < 16; p++) {
      const int off = p * 4096 + tid * 8;
      *(f16x8*)(&w2f[off]) = *(const f16x8*)(src + off);
    }
  }
  // --- stage W1 row tables (f16)
  if (tid < 128) {
    const int c8 = tid << 3;
    const float4 a0 = *(const float4*)(W1 + c8);
    const float4 a1 = *(const float4*)(W1 + c8 + 4);
    const float4 g0 = *(const float4*)(b1 + c8);
    const float4 g1 = *(const float4*)(b1 + c8 + 4);
    f16x8 oa, og;
    oa[0] = (f16)a0.x; oa[1] = (f16)a0.y; oa[2] = (f16)a0.z; oa[3] = (f16)a0.w;
    oa[4] = (f16)a1.x; oa[5] = (f16)a1.y; oa[6] = (f16)a1.z; oa[7] = (f16)a1.w;
    og[0] = (f16)g0.x; og[1] = (f16)g0.y; og[2] = (f16)g0.z; og[3] = (f16)g0.w;
    og[4] = (f16)g1.x; og[5] = (f16)g1.y; og[6] = (f16)g1.z; og[7] = (f16)g1.w;
    *(f16x8*)(&w1a[c8]) = oa;
    *(f16x8*)(&b1t[c8]) = og;
  } else if (tid < 256) {
    const int c8 = (tid - 128) << 3;
    const float4 a0 = *(const float4*)(W1 + 1024 + c8);
    const float4 a1 = *(const float4*)(W1 + 1024 + c8 + 4);
    f16x8 ob;
    ob[0] = (f16)a0.x; ob[1] = (f16)a0.y; ob[2] = (f16)a0.z; ob[3] = (f16)a0.w;
    ob[4] = (f16)a1.x; ob[5] = (f16)a1.y; ob[6] = (f16)a1.z; ob[7] = (f16)a1.w;
    *(f16x8*)(&w1bt[c8]) = ob;
  }
  __syncthreads();

  const int lane = tid & 63, wv = tid >> 6;  // 8 waves; wave owns 2 i-rows
  const int cL = lane & 15, q = lane >> 4;

  // per-lane x_j for the 8 j-groups (A-frag m-index = cL)
  f16 xjs[8];
  #pragma unroll
  for (int rg = 0; rg < 8; rg++) xjs[rg] = (f16)x[j0 + rg * 16 + cL];

  float b2v[4], w3v[4];
  #pragma unroll
  for (int cg = 0; cg < 4; cg++) {
    b2v[cg] = b2[nh * 64 + cg * 16 + cL];
    w3v[cg] = W3[nh * 64 + cg * 16 + cL];
  }
  const float badd = (nh == 0) ? b3[0] : 0.f;  // b3 added exactly once

  for (int ii = 0; ii < 2; ++ii) {
    const int i = i0 + wv * 2 + ii;
    const f16 xih = (f16)x[i];
    const f16x8 xiv = bcast8(xih);

    f32x4 acc[8][4];
    #pragma unroll
    for (int rg = 0; rg < 8; rg++)
      #pragma unroll
      for (int cg = 0; cg < 4; cg++) acc[rg][cg] = (f32x4){0.f, 0.f, 0.f, 0.f};

    #pragma unroll 2
    for (int kk = 0; kk < 32; ++kk) {
      const int o = kk * 32 + q * 8;
      const f16x8 w1av = *(const f16x8*)(&w1a[o]);
      const f16x8 b1v  = *(const f16x8*)(&b1t[o]);
      const f16x8 w1bv = *(const f16x8*)(&w1bt[o]);
      const f16x8 hav = xiv * w1av + b1v;          // 4x v_pk_fma_f16
      f16x8 bf[4];
      #pragma unroll
      for (int cg = 0; cg < 4; cg++)
        bf[cg] = *(const f16x8*)(&w2f[(cg * 32 + kk) * 512 + lane * 8]);
      #pragma unroll
      for (int rg = 0; rg < 8; rg++) {
        const f16x8 af = relu8(bcast8(xjs[rg]) * w1bv + hav);
        #pragma unroll
        for (int cg = 0; cg < 4; cg++)
          acc[rg][cg] = __builtin_amdgcn_mfma_f32_16x16x32_f16(af, bf[cg], acc[rg][cg], 0, 0, 0);
      }
    }

    // --- epilogue row i: partial dot over this nh's 64 n
    #pragma unroll
    for (int rg = 0; rg < 8; rg++) {
      #pragma unroll
      for (int r = 0; r < 4; r++) {
        float ssum = 0.f;
        #pragma unroll
        for (int cg = 0; cg < 4; cg++)
          ssum = fmaf(fmaxf(acc[rg][cg][r] + b2v[cg], 0.f), w3v[cg], ssum);
        ssum += __shfl_xor(ssum, 1, 64);
        ssum += __shfl_xor(ssum, 2, 64);
        ssum += __shfl_xor(ssum, 4, 64);
        ssum += __shfl_xor(ssum, 8, 64);
        if (cL == 0) {
          const int j = j0 + rg * 16 + q * 4 + r;  // C row = q*4 + reg
          if (j >= i) Kp[i * 512 + j] = ssum + badd;
        }
      }
    }
  }
}

// ---------------------------------------------------------------------------
// atta: C = K^T K, K = Kp0 + Kp1 (summed on load). Below-diagonal entries
// UNWRITTEN -> masked to 0. Symmetry (pb<=qb + mirror), i-loop stops at pb+32.
// ---------------------------------------------------------------------------
__global__ __launch_bounds__(256) void k_atta(const float* __restrict__ K0,
                                              const float* __restrict__ K1,
                                              float* __restrict__ C) {
  const int pb = blockIdx.x * 32, qb = blockIdx.y * 32;
  if (pb > qb) return;
  __shared__ float sp[32][33], sq[32][33];
  const int tid = threadIdx.x;
  const int tx = tid & 15, ty = tid >> 4;
  float c00 = 0.f, c01 = 0.f, c10 = 0.f, c11 = 0.f;
  for (int i0 = 0; i0 < pb + 32; i0 += 32) {
    #pragma unroll
    for (int r = 0; r < 4; r++) {
      const int e = tid + 256 * r, ii = e >> 5, pp = e & 31;
      const int irow = i0 + ii;
      const int ip = irow * 512 + pb + pp, iq = irow * 512 + qb + pp;
      sp[ii][pp] = (irow <= pb + pp) ? K0[ip] + K1[ip] : 0.f;
      sq[ii][pp] = (irow <= qb + pp) ? K0[iq] + K1[iq] : 0.f;
    }
    __syncthreads();
    #pragma unroll 8
    for (int ii = 0; ii < 32; ii++) {
      const float a0 = sp[ii][ty * 2], a1 = sp[ii][ty * 2 + 1];
      const float b0 = sq[ii][tx * 2], b1 = sq[ii][tx * 2 + 1];
      c00 = fmaf(a0, b0, c00); c01 = fmaf(a0, b1, c01);
      c10 = fmaf(a1, b0, c10); c11 = fmaf(a1, b1, c11);
    }
    __syncthreads();
  }
  const int p0 = pb + ty * 2, q0 = qb + tx * 2;
  C[p0 * 512 + q0] = c00;       C[p0 * 512 + q0 + 1] = c01;
  C[(p0 + 1) * 512 + q0] = c10; C[(p0 + 1) * 512 + q0 + 1] = c11;
  C[q0 * 512 + p0] = c00;       C[(q0 + 1) * 512 + p0] = c01;
  C[q0 * 512 + p0 + 1] = c10;   C[(q0 + 1) * 512 + p0 + 1] = c11;
}

extern "C" void kernel_launch(void* const* d_in, const int* in_sizes, int n_in,
                              void* d_out, int out_size, void* d_ws, size_t ws_size,
                              hipStream_t stream) {
  const float* x  = (const float*)d_in[0];
  const float* W1 = (const float*)d_in[1];
  const float* b1 = (const float*)d_in[2];
  const float* W2 = (const float*)d_in[3];
  const float* b2 = (const float*)d_in[4];
  const float* W3 = (const float*)d_in[5];
  const float* b3 = (const float*)d_in[6];
  float* out = (float*)d_out;
  char* ws = (char*)d_ws;

  f16* Wtp   = (f16*)ws;                           // 256 KB packed W2 B-fragments
  float* Kp0 = (float*)(ws + (256 << 10));         // 1 MB partial (n 0..63)
  float* Kp1 = (float*)(ws + (256 << 10) + (1 << 20));  // 1 MB partial (n 64..127)

  k_prep<<<64, 256, 0, stream>>>(W2, Wtp);
  k_fused<<<dim3(4, 32, 2), 512, 0, stream>>>(x, W1, b1, b2, W3, b3, Wtp, Kp0, Kp1);
  k_atta<<<dim3(16, 16), 256, 0, stream>>>(Kp0, Kp1, out);
}